// Round 1
// baseline (283.714 us; speedup 1.0000x reference)
//
#include <hip/hip_runtime.h>
#include <math.h>

// Problem constants (fixed by setup_inputs)
constexpr int HOPS  = 3;
constexpr int NTAB  = HOPS + 1;   // 4 embedding tables
constexpr int VOCAB = 50257;
constexpr int DIM   = 128;
constexpr int NB    = 32;         // batch
constexpr int NM    = 512;        // story slots
constexpr int NS    = 6;          // tokens per story slot
constexpr int NT    = 128;        // trees
constexpr int NL    = 64;         // tokens per tree
constexpr int SLOTS = NM + NT;    // 640
constexpr int SLOTS_PER_BLOCK = 4;              // 4 waves/block, 1 wave per slot
constexpr int BLOCKS_PER_B = SLOTS / SLOTS_PER_BLOCK;  // 160
constexpr size_t TABSTRIDE = (size_t)NB * SLOTS * DIM; // msum stride per table

// ---------------------------------------------------------------------------
// Kernel A: msum[h][b][slot][d] = sum_t C[h][tok(b,slot,t)][d]
// One 64-lane wave per (b, slot); each lane owns a float2 of the 128-dim row.
// All 4 tables accumulated in one pass (indices identical across tables).
// ---------------------------------------------------------------------------
__global__ __launch_bounds__(256) void gather_sum_kernel(
    const float* __restrict__ C,      // [4][VOCAB][DIM]
    const int*   __restrict__ story,  // [NB][NM][NS]
    const int*   __restrict__ kb,     // [NB][NT][NL]
    float*       __restrict__ msum)   // [4][NB][SLOTS][DIM]
{
    const int wave = threadIdx.x >> 6;
    const int lane = threadIdx.x & 63;
    const int b    = blockIdx.x / BLOCKS_PER_B;
    const int slot = (blockIdx.x % BLOCKS_PER_B) * SLOTS_PER_BLOCK + wave;
    const int d    = lane * 2;

    float2 a0 = {0.f, 0.f}, a1 = {0.f, 0.f}, a2 = {0.f, 0.f}, a3 = {0.f, 0.f};
    const float* Cd = C + d;
    constexpr size_t TS = (size_t)VOCAB * DIM;

    if (slot < NM) {
        const int* idx = story + ((size_t)b * NM + slot) * NS;
        #pragma unroll
        for (int t = 0; t < NS; ++t) {
            const size_t r = (size_t)idx[t] * DIM;
            float2 v0 = *(const float2*)(Cd + r);
            float2 v1 = *(const float2*)(Cd + r + TS);
            float2 v2 = *(const float2*)(Cd + r + 2 * TS);
            float2 v3 = *(const float2*)(Cd + r + 3 * TS);
            a0.x += v0.x; a0.y += v0.y;
            a1.x += v1.x; a1.y += v1.y;
            a2.x += v2.x; a2.y += v2.y;
            a3.x += v3.x; a3.y += v3.y;
        }
    } else {
        const int* idx = kb + ((size_t)b * NT + (slot - NM)) * NL;
        #pragma unroll 8
        for (int t = 0; t < NL; ++t) {
            const size_t r = (size_t)idx[t] * DIM;
            float2 v0 = *(const float2*)(Cd + r);
            float2 v1 = *(const float2*)(Cd + r + TS);
            float2 v2 = *(const float2*)(Cd + r + 2 * TS);
            float2 v3 = *(const float2*)(Cd + r + 3 * TS);
            a0.x += v0.x; a0.y += v0.y;
            a1.x += v1.x; a1.y += v1.y;
            a2.x += v2.x; a2.y += v2.y;
            a3.x += v3.x; a3.y += v3.y;
        }
    }

    const size_t o = ((size_t)b * SLOTS + slot) * DIM + d;
    *(float2*)(msum + o)                 = a0;
    *(float2*)(msum + o + TABSTRIDE)     = a1;
    *(float2*)(msum + o + 2 * TABSTRIDE) = a2;
    *(float2*)(msum + o + 3 * TABSTRIDE) = a3;
}

// ---------------------------------------------------------------------------
// Kernel B: the 3-hop attention chain. One block per batch element.
// hop 0: u=0 -> softmax is exactly uniform -> o_k = mean over slots of mC.
// ---------------------------------------------------------------------------
__global__ __launch_bounds__(256) void hops_kernel(
    const float* __restrict__ msum,   // [4][NB][SLOTS][DIM]
    float*       __restrict__ out)    // [NB][DIM]
{
    __shared__ float u_s[DIM];
    __shared__ float probs[SLOTS];
    __shared__ float red[4];
    __shared__ float okk[2][DIM];

    const int b  = blockIdx.x;
    const int t  = threadIdx.x;
    const int wv = t >> 6;
    const int ln = t & 63;

    if (t < DIM) u_s[t] = 0.f;
    __syncthreads();

    for (int hop = 0; hop < HOPS; ++hop) {
        const float* mC = msum + (size_t)(hop + 1) * TABSTRIDE + (size_t)b * SLOTS * DIM;
        float inv_sum;

        if (hop == 0) {
            inv_sum = 1.0f / SLOTS;   // softmax of all-zero scores is uniform
        } else {
            const float* mA = msum + (size_t)hop * TABSTRIDE + (size_t)b * SLOTS * DIM;
            // scores[m] = dot(mA[m], u)
            for (int m = t; m < SLOTS; m += 256) {
                const float4* row = (const float4*)(mA + (size_t)m * DIM);
                float acc = 0.f;
                #pragma unroll
                for (int i = 0; i < DIM / 4; ++i) {
                    float4 r = row[i];
                    float4 uu = ((const float4*)u_s)[i];
                    acc = fmaf(r.x, uu.x, acc);
                    acc = fmaf(r.y, uu.y, acc);
                    acc = fmaf(r.z, uu.z, acc);
                    acc = fmaf(r.w, uu.w, acc);
                }
                probs[m] = acc;
            }
            __syncthreads();                       // (1) scores visible

            // block max
            float lmax = -INFINITY;
            for (int m = t; m < SLOTS; m += 256) lmax = fmaxf(lmax, probs[m]);
            #pragma unroll
            for (int off = 32; off > 0; off >>= 1) lmax = fmaxf(lmax, __shfl_xor(lmax, off));
            if (ln == 0) red[wv] = lmax;
            __syncthreads();                       // (2) red visible
            lmax = fmaxf(fmaxf(red[0], red[1]), fmaxf(red[2], red[3]));
            __syncthreads();                       // (3) all done reading red

            // exp + block sum (each thread touches only its own slots)
            float lsum = 0.f;
            for (int m = t; m < SLOTS; m += 256) {
                float e = expf(probs[m] - lmax);
                probs[m] = e;
                lsum += e;
            }
            #pragma unroll
            for (int off = 32; off > 0; off >>= 1) lsum += __shfl_xor(lsum, off);
            if (ln == 0) red[wv] = lsum;
            __syncthreads();                       // (4) red + probs visible
            lsum = red[0] + red[1] + red[2] + red[3];
            inv_sum = 1.0f / lsum;
        }

        // o_k[d] = inv_sum * sum_m probs[m] * mC[m][d]; 2 half-ranges of m
        const int d    = t & (DIM - 1);
        const int half = t >> 7;
        float acc = 0.f;
        if (hop == 0) {
            for (int m = half * (SLOTS / 2); m < (half + 1) * (SLOTS / 2); ++m)
                acc += mC[(size_t)m * DIM + d];
        } else {
            for (int m = half * (SLOTS / 2); m < (half + 1) * (SLOTS / 2); ++m)
                acc = fmaf(probs[m], mC[(size_t)m * DIM + d], acc);
        }
        okk[half][d] = acc;
        __syncthreads();                           // (5) okk visible; red free
        if (t < DIM) u_s[t] += (okk[0][t] + okk[1][t]) * inv_sum;
        __syncthreads();                           // (6) u visible for next hop
    }

    if (t < DIM) out[b * DIM + t] = u_s[t];
}

extern "C" void kernel_launch(void* const* d_in, const int* in_sizes, int n_in,
                              void* d_out, int out_size, void* d_ws, size_t ws_size,
                              hipStream_t stream) {
    const float* C     = (const float*)d_in[0];   // [4][VOCAB][DIM] fp32
    const int*   story = (const int*)d_in[1];     // [32][512][6]
    const int*   kb    = (const int*)d_in[2];     // [32][128][64]
    float*       out   = (float*)d_out;           // [32][128] fp32
    float*       msum  = (float*)d_ws;            // [4][32][640][128] fp32 = 40 MiB

    gather_sum_kernel<<<NB * BLOCKS_PER_B, 256, 0, stream>>>(C, story, kb, msum);
    hops_kernel<<<NB, 256, 0, stream>>>(msum, out);
}

// Round 2
// 231.773 us; speedup vs baseline: 1.2241x; 1.2241x over previous
//
#include <hip/hip_runtime.h>
#include <math.h>

// Problem constants (fixed by setup_inputs)
constexpr int HOPS  = 3;
constexpr int VOCAB = 50257;
constexpr int DIM   = 128;
constexpr int NB    = 32;         // batch
constexpr int NM    = 512;        // story slots
constexpr int NS    = 6;          // tokens per story slot
constexpr int NT    = 128;        // trees
constexpr int NL    = 64;         // tokens per tree
constexpr int SLOTS = NM + NT;    // 640
constexpr size_t TS = (size_t)VOCAB * DIM;              // table stride in C
constexpr size_t TABSTRIDE = (size_t)NB * SLOTS * DIM;  // msum stride per table
constexpr int CHUNKS = SLOTS / 64;                      // 10 slot-chunks of 64

// msum holds gather-sums for tables 1..3 only (table 0 is dead: u=0 at hop 0
// makes the first softmax uniform independent of m_A). msum index k = C[k+1].

__device__ __forceinline__ void addf4(float4& a, const float4& v) {
    a.x += v.x; a.y += v.y; a.z += v.z; a.w += v.w;
}
__device__ __forceinline__ void halfred(float4& a) {   // sum lane halves (xor 32)
    a.x += __shfl_xor(a.x, 32); a.y += __shfl_xor(a.y, 32);
    a.z += __shfl_xor(a.z, 32); a.w += __shfl_xor(a.w, 32);
}

// ---------------------------------------------------------------------------
// Story gather: one wave per story slot. Lane split: half = token parity,
// 32 lanes × float4 cover the 128-dim row. 3 tables accumulated per token.
// ---------------------------------------------------------------------------
__global__ __launch_bounds__(256) void story_gather(
    const float* __restrict__ C, const int* __restrict__ story,
    float* __restrict__ msum)
{
    const int wave = threadIdx.x >> 6, lane = threadIdx.x & 63;
    const int g    = blockIdx.x * 4 + wave;       // b*NM + slot
    const int b    = g >> 9;                      // /512
    const int slot = g & (NM - 1);
    const int half = lane >> 5, q = lane & 31;

    const int* idx = story + (size_t)g * NS;
    int tok = (lane < NS) ? idx[lane] : 0;

    const float* Cb = C + TS + (size_t)q * 4;     // table 1 base, this lane's dims
    float4 a0 = {0,0,0,0}, a1 = {0,0,0,0}, a2 = {0,0,0,0};
    #pragma unroll
    for (int i = 0; i < NS / 2; ++i) {
        int s = __shfl(tok, 2 * i + half);
        const float* p = Cb + (size_t)s * DIM;
        addf4(a0, *(const float4*)(p));
        addf4(a1, *(const float4*)(p + TS));
        addf4(a2, *(const float4*)(p + 2 * TS));
    }
    halfred(a0); halfred(a1); halfred(a2);
    if (half == 0) {
        const size_t o = ((size_t)b * SLOTS + slot) * DIM + q * 4;
        *(float4*)(msum + o)                 = a0;
        *(float4*)(msum + o + TABSTRIDE)     = a1;
        *(float4*)(msum + o + 2 * TABSTRIDE) = a2;
    }
}

// ---------------------------------------------------------------------------
// Tree gather: one 4-wave block per tree slot; each wave takes 16 of the 64
// tokens (2-token lane split), LDS reduction across waves at the end.
// ---------------------------------------------------------------------------
__global__ __launch_bounds__(256) void tree_gather(
    const float* __restrict__ C, const int* __restrict__ kb,
    float* __restrict__ msum)
{
    const int wave = threadIdx.x >> 6, lane = threadIdx.x & 63;
    const int g  = blockIdx.x;                    // b*NT + tree
    const int b  = g >> 7;                        // /128
    const int tr = g & (NT - 1);
    const int half = lane >> 5, q = lane & 31;

    const int* idx = kb + (size_t)g * NL + wave * 16;
    int tok = (lane < 16) ? idx[lane] : 0;

    const float* Cb = C + TS + (size_t)q * 4;
    float4 a0 = {0,0,0,0}, a1 = {0,0,0,0}, a2 = {0,0,0,0};
    #pragma unroll
    for (int i = 0; i < 8; ++i) {
        int s = __shfl(tok, 2 * i + half);
        const float* p = Cb + (size_t)s * DIM;
        addf4(a0, *(const float4*)(p));
        addf4(a1, *(const float4*)(p + TS));
        addf4(a2, *(const float4*)(p + 2 * TS));
    }
    halfred(a0); halfred(a1); halfred(a2);

    __shared__ float lds[4][3][DIM];
    if (half == 0) {
        *(float4*)(&lds[wave][0][q * 4]) = a0;
        *(float4*)(&lds[wave][1][q * 4]) = a1;
        *(float4*)(&lds[wave][2][q * 4]) = a2;
    }
    __syncthreads();
    const int t = threadIdx.x;
    if (t < DIM) {
        const size_t o = ((size_t)b * SLOTS + NM + tr) * DIM + t;
        #pragma unroll
        for (int tab = 0; tab < 3; ++tab) {
            msum[o + (size_t)tab * TABSTRIDE] =
                lds[0][tab][t] + lds[1][tab][t] + lds[2][tab][t] + lds[3][tab][t];
        }
    }
}

// ---------------------------------------------------------------------------
// Hop 0: softmax(0) is uniform -> u = (1/SLOTS) * sum_m mC[m]. Partial sums
// per 64-slot chunk, atomicAdd into u (= d_out, zeroed before).
// ---------------------------------------------------------------------------
__global__ __launch_bounds__(256) void hop0_uniform(
    const float* __restrict__ msum, float* __restrict__ u)
{
    const int b = blockIdx.x / CHUNKS, chunk = blockIdx.x % CHUNKS;
    const int t = threadIdx.x, d = t & (DIM - 1), sub = t >> 7;
    const float* mC = msum + ((size_t)b * SLOTS + chunk * 64 + sub * 32) * DIM + d;
    float acc = 0.f;
    #pragma unroll
    for (int m = 0; m < 32; ++m) acc += mC[(size_t)m * DIM];
    __shared__ float red[256];
    red[t] = acc;
    __syncthreads();
    if (t < DIM) atomicAdd(&u[b * DIM + d], (red[t] + red[t + 128]) * (1.f / SLOTS));
}

// ---------------------------------------------------------------------------
// Scores: sc[b][m] = dot(mA[b][m], u[b]). One wave per slot.
// ---------------------------------------------------------------------------
__global__ __launch_bounds__(256) void scores_k(
    const float* __restrict__ msum, const float* __restrict__ u,
    float* __restrict__ sc, int tab)
{
    const int wave = threadIdx.x >> 6, lane = threadIdx.x & 63;
    const int g = blockIdx.x * 4 + wave;          // b*SLOTS + m
    const int b = g / SLOTS;
    float2 v  = *(const float2*)(msum + (size_t)tab * TABSTRIDE + (size_t)g * DIM + lane * 2);
    float2 uu = *(const float2*)(u + b * DIM + lane * 2);
    float acc = fmaf(v.x, uu.x, v.y * uu.y);
    #pragma unroll
    for (int off = 32; off > 0; off >>= 1) acc += __shfl_xor(acc, off);
    if (lane == 0) sc[g] = acc;
}

// ---------------------------------------------------------------------------
// Softmax over 640 slots, one block per b; normalizes sc in place.
// ---------------------------------------------------------------------------
__global__ __launch_bounds__(256) void softmax_k(float* __restrict__ sc)
{
    const int b = blockIdx.x, t = threadIdx.x, wv = t >> 6, ln = t & 63;
    float* s = sc + b * SLOTS;
    __shared__ float red[4];

    float v0 = s[t], v1 = s[t + 256];
    float v2 = (t < SLOTS - 512) ? s[t + 512] : -INFINITY;
    float lmax = fmaxf(fmaxf(v0, v1), v2);
    #pragma unroll
    for (int off = 32; off > 0; off >>= 1) lmax = fmaxf(lmax, __shfl_xor(lmax, off));
    if (ln == 0) red[wv] = lmax;
    __syncthreads();
    lmax = fmaxf(fmaxf(red[0], red[1]), fmaxf(red[2], red[3]));
    __syncthreads();

    float e0 = expf(v0 - lmax), e1 = expf(v1 - lmax);
    float e2 = (t < SLOTS - 512) ? expf(v2 - lmax) : 0.f;
    float lsum = e0 + e1 + e2;
    #pragma unroll
    for (int off = 32; off > 0; off >>= 1) lsum += __shfl_xor(lsum, off);
    if (ln == 0) red[wv] = lsum;
    __syncthreads();
    const float inv = 1.0f / (red[0] + red[1] + red[2] + red[3]);

    s[t] = e0 * inv; s[t + 256] = e1 * inv;
    if (t < SLOTS - 512) s[t + 512] = e2 * inv;
}

// ---------------------------------------------------------------------------
// Weighted sum: u[b] += sum_m probs[b][m] * mC[b][m]. Partial per 64-slot
// chunk, atomicAdd into u.
// ---------------------------------------------------------------------------
__global__ __launch_bounds__(256) void weighted_k(
    const float* __restrict__ msum, const float* __restrict__ probs,
    float* __restrict__ u, int tab)
{
    const int b = blockIdx.x / CHUNKS, chunk = blockIdx.x % CHUNKS;
    const int t = threadIdx.x, d = t & (DIM - 1), sub = t >> 7;
    __shared__ float p[64];
    if (t < 64) p[t] = probs[b * SLOTS + chunk * 64 + t];
    __syncthreads();
    const float* mC = msum + (size_t)tab * TABSTRIDE +
                      ((size_t)b * SLOTS + chunk * 64 + sub * 32) * DIM + d;
    float acc = 0.f;
    #pragma unroll
    for (int m = 0; m < 32; ++m) acc = fmaf(p[sub * 32 + m], mC[(size_t)m * DIM], acc);
    __shared__ float red[256];
    red[t] = acc;
    __syncthreads();
    if (t < DIM) atomicAdd(&u[b * DIM + d], red[t] + red[t + 128]);
}

extern "C" void kernel_launch(void* const* d_in, const int* in_sizes, int n_in,
                              void* d_out, int out_size, void* d_ws, size_t ws_size,
                              hipStream_t stream) {
    const float* C     = (const float*)d_in[0];   // [4][VOCAB][DIM] fp32
    const int*   story = (const int*)d_in[1];     // [32][512][6]
    const int*   kb    = (const int*)d_in[2];     // [32][128][64]
    float*       u     = (float*)d_out;           // [32][128] fp32 — also the accumulator
    float*       msum  = (float*)d_ws;            // [3][32][640][128] fp32 = 31.5 MiB
    float*       sc    = msum + 3 * TABSTRIDE;    // [32][640] scores/probs

    hipMemsetAsync(u, 0, (size_t)NB * DIM * sizeof(float), stream);

    story_gather<<<NB * NM / 4, 256, 0, stream>>>(C, story, msum);
    tree_gather<<<NB * NT, 256, 0, stream>>>(C, kb, msum);

    hop0_uniform<<<NB * CHUNKS, 256, 0, stream>>>(msum /*tab0 = C[1]*/, u);

    for (int hop = 1; hop < HOPS; ++hop) {
        // A-table of hop h is C[h] -> msum index h-1; V-table C[h+1] -> index h
        scores_k<<<NB * SLOTS / 4, 256, 0, stream>>>(msum, u, sc, hop - 1);
        softmax_k<<<NB, 256, 0, stream>>>(sc);
        weighted_k<<<NB * CHUNKS, 256, 0, stream>>>(msum, sc, u, hop);
    }
}